// Round 13
// baseline (2712.132 us; speedup 1.0000x reference)
//
#include <hip/hip_runtime.h>

#define HID 512
#define NB  256
#define TT  256
#define DIN 64
#define SLOT_SH 131072               // shorts per h panel slot (256 KB)
#define NSLOT 8                      // rotation depth; fence every NSLOT iters

typedef __attribute__((ext_vector_type(8))) short short8;
typedef __attribute__((ext_vector_type(4))) float f32x4;
typedef __attribute__((ext_vector_type(16))) float f32x16;

__device__ __forceinline__ unsigned short f2bf(float f) {
    unsigned int u = __float_as_uint(f);
    u += 0x7FFF + ((u >> 16) & 1);
    return (unsigned short)(u >> 16);
}
__device__ __forceinline__ float bf2f(unsigned short h) {
    return __uint_as_float(((unsigned int)h) << 16);
}

// ---- LLC-coherent (cross-XCD) 4B access, explicit sc0/sc1 cache bits ----
__device__ __forceinline__ void st_u32_llc(unsigned* p, unsigned v) {
    asm volatile("global_store_dword %0, %1, off sc0 sc1" :: "v"(p), "v"(v) : "memory");
}
__device__ __forceinline__ unsigned ld_u32_llc(const unsigned* p) {
    unsigned v;
    asm volatile("global_load_dword %0, %1, off sc0 sc1\n\ts_waitcnt vmcnt(0)"
                 : "=v"(v) : "v"(p) : "memory");
    return v;
}

#define MFMA32(acc, a, b) acc = __builtin_amdgcn_mfma_f32_32x32x16_bf16(a, b, acc, 0, 0, 0)
#define MFMA16(acc, a, b) acc = __builtin_amdgcn_mfma_f32_16x16x32_bf16(a, b, acc, 0, 0, 0)

// LDS (shorts): sWC h/l 32kf*512 each; sWx h/l 4kf*512; sW1 h/l 16kt*512; sG floats
#define SWC_N 16384
#define SWX_N 2048
#define SW1_N 8192
#define SG_F  9216                   // 8 tiles * 32 cols * 36
#define LDS_BYTES ((SWC_N * 2 + SWX_N * 2 + SW1_N * 2) * 2 + SG_F * 4)

// packed 2-lane h store: lanes (l, l+1) hold adjacent j; even lane stores u32
__device__ __forceinline__ void store_h_pair(unsigned short* buf, size_t hoff,
                                             unsigned short v, int l) {
    unsigned int hv = (unsigned int)v;
    unsigned int up = __shfl_down(hv, 1);
    if ((l & 1) == 0)
        st_u32_llc((unsigned*)(buf + hoff), hv | (up << 16));
}

// wait: 128 lanes poll one flag each (LLC loads, no cache pollution), then barrier
__device__ __forceinline__ void flag_wait(unsigned* fset, int target) {
    if (threadIdx.x < 128) {
        unsigned* p = fset + threadIdx.x;
        while ((int)ld_u32_llc(p) < target) __builtin_amdgcn_s_sleep(2);
    }
    __syncthreads();
}

__global__ __launch_bounds__(512, 2) void lstm_persistent(
    const float* __restrict__ x,
    const float* __restrict__ Wih0, const float* __restrict__ Whh0,
    const float* __restrict__ bih0, const float* __restrict__ bhh0,
    const float* __restrict__ Wih1, const float* __restrict__ Whh1,
    const float* __restrict__ bih1, const float* __restrict__ bhh1,
    const float* __restrict__ headw, const float* __restrict__ headb,
    unsigned short* h0base, unsigned short* h1base,
    unsigned* gf, float* __restrict__ out)
{
    extern __shared__ unsigned short lds[];
    unsigned short* sWCh = lds;
    unsigned short* sWCl = sWCh + SWC_N;
    unsigned short* sWxh = sWCl + SWC_N;
    unsigned short* sWxl = sWxh + SWX_N;
    unsigned short* sW1h = sWxl + SWX_N;
    unsigned short* sW1l = sW1h + SW1_N;
    float* sG = (float*)(sW1l + SW1_N);   // [4bt*2kh tiles][32 cols][36]

    const int tid = threadIdx.x;
    const int l   = tid & 63;
    const int w   = tid >> 6;           // wave 0..7
    const int bid = blockIdx.x;
    const int g   = bid & 1;            // batch group (128 rows)
    const int jb  = bid >> 1;           // j-block 0..127 (hidden units jb*4..+3)
    const int bt32 = w & 3;             // 32-batch tile
    const int kh   = w >> 2;            // K-half (0: k<256, 1: k>=256)

    unsigned* f0g = gf + g * 128;
    unsigned* f1g = gf + 256 + g * 128;

    // ---------------- weight preload ----------------
    const int r32 = l & 31;
    const int ks2 = (l >> 5) * 8;       // k-sub for 32x32 frags
    {
        const int gate = (r32 & 15) >> 2, unit = r32 & 3;
        const int nrow = gate * HID + jb * 4 + unit;
        // combined [W0hh rows 0-15 | W1ih rows 16-31], K=512 as 32 frags of 16
        for (int kf = w; kf < 32; kf += 8) {
            const float* src = ((r32 < 16) ? (Whh0 + (size_t)nrow * HID)
                                           : (Wih1 + (size_t)nrow * HID)) + kf * 16 + ks2;
            float v[8];
            *(float4*)&v[0] = *(const float4*)src;
            *(float4*)&v[4] = *(const float4*)(src + 4);
            union { unsigned short u[8]; uint4 q; } ph, pl;
            #pragma unroll
            for (int e = 0; e < 8; ++e) {
                unsigned short h = f2bf(v[e]);
                ph.u[e] = h; pl.u[e] = f2bf(v[e] - bf2f(h));
            }
            *(uint4*)&sWCh[(kf * 64 + l) * 8] = ph.q;
            *(uint4*)&sWCl[(kf * 64 + l) * 8] = pl.q;
        }
        // padded x-weights [W0ih | zeros], K=64 as 4 frags
        if (w < 4) {
            const int kf = w;
            union { unsigned short u[8]; uint4 q; } ph, pl;
            if (r32 < 16) {
                const float* src = Wih0 + (size_t)nrow * DIN + kf * 16 + ks2;
                float v[8];
                *(float4*)&v[0] = *(const float4*)src;
                *(float4*)&v[4] = *(const float4*)(src + 4);
                #pragma unroll
                for (int e = 0; e < 8; ++e) {
                    unsigned short h = f2bf(v[e]);
                    ph.u[e] = h; pl.u[e] = f2bf(v[e] - bf2f(h));
                }
            } else {
                ph.q = uint4{0, 0, 0, 0}; pl.q = uint4{0, 0, 0, 0};
            }
            *(uint4*)&sWxh[(kf * 64 + l) * 8] = ph.q;
            *(uint4*)&sWxl[(kf * 64 + l) * 8] = pl.q;
        }
        // W1hh as 16-row 16x16x32 frags (16 kt of K=32)
        const int r16 = l & 15;
        const int n1 = (r16 >> 2) * HID + jb * 4 + (r16 & 3);
        const int ks4 = (l >> 4) * 8;
        for (int kt = w; kt < 16; kt += 8) {
            const float* src = Whh1 + (size_t)n1 * HID + kt * 32 + ks4;
            float v[8];
            *(float4*)&v[0] = *(const float4*)src;
            *(float4*)&v[4] = *(const float4*)(src + 4);
            union { unsigned short u[8]; uint4 q; } ph, pl;
            #pragma unroll
            for (int e = 0; e < 8; ++e) {
                unsigned short h = f2bf(v[e]);
                ph.u[e] = h; pl.u[e] = f2bf(v[e] - bf2f(h));
            }
            *(uint4*)&sW1h[(kt * 64 + l) * 8] = ph.q;
            *(uint4*)&sW1l[(kt * 64 + l) * 8] = pl.q;
        }
    }

    // epilogue constants: thread -> (b_loc, jj)
    const int jj    = tid & 3;
    const int b_loc = tid >> 2;         // 0..127 within group
    const int j_glob = jb * 4 + jj;
    const int bt32e = b_loc >> 5, rowe = b_loc & 31;
    float bias0[4], bias1[4];
    #pragma unroll
    for (int gi = 0; gi < 4; ++gi) {
        const int nn = gi * HID + j_glob;
        bias0[gi] = bih0[nn] + bhh0[nn];
        bias1[gi] = bih1[nn] + bhh1[nn];
    }
    float c0 = 0.f, c1 = 0.f;

    // h0 store offset (32x32 A layout): [g][bt32][kf=j>>4][lane=(b&31)|((j>>3&1)<<5)][j&7]
    const size_t hoff0 = ((((size_t)g * 4 + (b_loc >> 5)) * 32 + (j_glob >> 4)) * 64
                          + ((b_loc & 31) | (((j_glob >> 3) & 1) << 5))) * 8 + (j_glob & 7);
    // h1 store offset (16x16 A layout, unchanged from r12)
    const int b_glob = g * 128 + b_loc;
    const size_t hoff1 = ((((size_t)(b_glob >> 4)) * 16 + (j_glob >> 5)) * 64
                          + ((b_glob & 15) | (((j_glob >> 3) & 3) << 4))) * 8 + (j_glob & 7);

    // x prefetch (K-lo waves only): xv[kf][e] = x[b][kf*16 + (l>>5)*8 + e]
    const int xrow = g * 128 + bt32 * 32 + (l & 31);
    float xv[4][8];
    if (kh == 0) {
        const float* sx = x + ((size_t)xrow * TT + 0) * DIN + ks2;
        #pragma unroll
        for (int kf = 0; kf < 4; ++kf) {
            *(float4*)&xv[kf][0] = *(const float4*)(sx + kf * 16);
            *(float4*)&xv[kf][4] = *(const float4*)(sx + kf * 16 + 4);
        }
    }

    __syncthreads();                    // weights ready

    const int tile = bt32 * 2 + kh;
    for (int it = 0; it <= TT; ++it) {
        // ---- wait 1: layer0 of it-1 done (signaled mid-iteration -> fast)
        flag_wait(f0g, it);

        const unsigned short* h0c = h0base + (size_t)((it + 7) & 7) * SLOT_SH;  // h0[it-1]
        unsigned short* h0n       = h0base + (size_t)(it & 7) * SLOT_SH;        // h0[it]
        const unsigned short* h1c = h1base + (size_t)((it + 6) & 7) * SLOT_SH;  // h1[it-2]
        unsigned short* h1n       = h1base + (size_t)((it + 7) & 7) * SLOT_SH;  // h1[it-1]

        // ---- combined chain: A = h0[it-1] (32 batch x K-half), B = [W0hh|W1ih]
        short8 fA[16];
        #pragma unroll
        for (int kf = 0; kf < 16; ++kf) {
            const size_t o = ((((size_t)g * 4 + bt32) * 32 + kh * 16 + kf) * 64 + l) * 8;
            fA[kf] = *(const short8*)&h0c[o];
        }
        f32x16 aC0, aC1;
        #pragma unroll
        for (int i = 0; i < 16; ++i) { aC0[i] = 0.f; aC1[i] = 0.f; }
        #pragma unroll
        for (int kf = 0; kf < 16; ++kf) {
            const int kfg = kh * 16 + kf;
            short8 bh = *(const short8*)&sWCh[(kfg * 64 + l) * 8];
            short8 bl = *(const short8*)&sWCl[(kfg * 64 + l) * 8];
            if (kf & 1) { MFMA32(aC1, fA[kf], bh); MFMA32(aC1, fA[kf], bl); }
            else        { MFMA32(aC0, fA[kf], bh); MFMA32(aC0, fA[kf], bl); }
        }
        // ---- x part (layer0 only; K-lo waves; 3-term split)
        if (kh == 0 && it < TT) {
            #pragma unroll
            for (int kf = 0; kf < 4; ++kf) {
                union { unsigned short u[8]; short8 s; } ah, al;
                #pragma unroll
                for (int e = 0; e < 8; ++e) {
                    unsigned short h = f2bf(xv[kf][e]);
                    ah.u[e] = h; al.u[e] = f2bf(xv[kf][e] - bf2f(h));
                }
                short8 bh = *(const short8*)&sWxh[(kf * 64 + l) * 8];
                short8 bl = *(const short8*)&sWxl[(kf * 64 + l) * 8];
                if (kf & 1) { MFMA32(aC1, ah.s, bh); MFMA32(aC1, ah.s, bl); MFMA32(aC1, al.s, bh); }
                else        { MFMA32(aC0, ah.s, bh); MFMA32(aC0, ah.s, bl); MFMA32(aC0, al.s, bh); }
            }
        }
        // ---- write combined acc to sG: col=l&31, row=(reg&3)+8*(reg>>2)+4*(l>>5)
        {
            f32x16 s = aC0 + aC1;
            #pragma unroll
            for (int i = 0; i < 4; ++i) {
                const int idx = (tile * 32 + (l & 31)) * 36 + 8 * i + 4 * (l >> 5);
                float4 v; v.x = s[4 * i]; v.y = s[4 * i + 1]; v.z = s[4 * i + 2]; v.w = s[4 * i + 3];
                *(float4*)&sG[idx] = v;
            }
        }
        __syncthreads();

        // ================= layer 0 epilogue, t = it =================
        if (it < TT) {
            const int i0 = (bt32e * 2) * 32 * 36 + rowe;
            const int i1 = (bt32e * 2 + 1) * 32 * 36 + rowe;
            const float gi_ = sG[i0 + jj * 36]        + sG[i1 + jj * 36]        + bias0[0];
            const float gf_ = sG[i0 + (4 + jj) * 36]  + sG[i1 + (4 + jj) * 36]  + bias0[1];
            const float gg_ = sG[i0 + (8 + jj) * 36]  + sG[i1 + (8 + jj) * 36]  + bias0[2];
            const float go_ = sG[i0 + (12 + jj) * 36] + sG[i1 + (12 + jj) * 36] + bias0[3];
            const float iG = 1.f / (1.f + expf(-gi_));
            const float fG = 1.f / (1.f + expf(-gf_));
            const float gT = tanhf(gg_);
            const float oG = 1.f / (1.f + expf(-go_));
            c0 = fmaf(fG, c0, iG * gT);
            const float h = oG * tanhf(c0);
            store_h_pair(h0n, hoff0, f2bf(h), l);
            // EARLY layer0-done signal
            asm volatile("s_waitcnt vmcnt(0)" ::: "memory");
            __syncthreads();
            if (tid == 0) st_u32_llc(f0g + jb, (unsigned)(it + 1));
        }

        // prefetch x[it+1]
        if (kh == 0 && it + 1 < TT) {
            const float* sx = x + ((size_t)xrow * TT + (it + 1)) * DIN + ks2;
            #pragma unroll
            for (int kf = 0; kf < 4; ++kf) {
                *(float4*)&xv[kf][0] = *(const float4*)(sx + kf * 16);
                *(float4*)&xv[kf][4] = *(const float4*)(sx + kf * 16 + 4);
            }
        }

        // ---- wait 2: layer1 of it-1 done (covers h1[it-2] writes)
        flag_wait(f1g, it);

        // ================= layer 1, t = it-1 =================
        if (it > 0) {
            // h1[it-2] part: 16x16x32, 2 batch sub-tiles share B registers
            const int tb0 = g * 8 + bt32 * 2;
            short8 fC0[8], fC1[8];
            #pragma unroll
            for (int q = 0; q < 8; ++q) {
                const int kt = kh * 8 + q;
                fC0[q] = *(const short8*)&h1c[(((size_t)tb0 * 16 + kt) * 64 + l) * 8];
                fC1[q] = *(const short8*)&h1c[((((size_t)tb0 + 1) * 16 + kt) * 64 + l) * 8];
            }
            f32x4 a1[2][2];
            #pragma unroll
            for (int s_ = 0; s_ < 2; ++s_) {
                a1[s_][0] = f32x4{0.f, 0.f, 0.f, 0.f};
                a1[s_][1] = f32x4{0.f, 0.f, 0.f, 0.f};
            }
            #pragma unroll
            for (int q = 0; q < 8; ++q) {
                const int kt = kh * 8 + q;
                short8 bh = *(const short8*)&sW1h[(kt * 64 + l) * 8];
                short8 bl = *(const short8*)&sW1l[(kt * 64 + l) * 8];
                if (q & 1) { MFMA16(a1[0][1], fC0[q], bh); MFMA16(a1[0][1], fC0[q], bl);
                             MFMA16(a1[1][1], fC1[q], bh); MFMA16(a1[1][1], fC1[q], bl); }
                else       { MFMA16(a1[0][0], fC0[q], bh); MFMA16(a1[0][0], fC0[q], bl);
                             MFMA16(a1[1][0], fC1[q], bh); MFMA16(a1[1][0], fC1[q], bl); }
            }
            // add into sG layer1 slots (cols 16-31); own-wave slots only
            #pragma unroll
            for (int s_ = 0; s_ < 2; ++s_) {
                #pragma unroll
                for (int q = 0; q < 4; ++q) {
                    const int row = s_ * 16 + (l >> 4) * 4 + q;
                    const int idx = (tile * 32 + 16 + (l & 15)) * 36 + row;
                    sG[idx] += a1[s_][0][q] + a1[s_][1][q];
                }
            }
            __syncthreads();
            // layer1 epilogue
            {
                const int i0 = (bt32e * 2) * 32 * 36 + rowe;
                const int i1 = (bt32e * 2 + 1) * 32 * 36 + rowe;
                const float gi_ = sG[i0 + (16 + jj) * 36]      + sG[i1 + (16 + jj) * 36]      + bias1[0];
                const float gf_ = sG[i0 + (16 + 4 + jj) * 36]  + sG[i1 + (16 + 4 + jj) * 36]  + bias1[1];
                const float gg_ = sG[i0 + (16 + 8 + jj) * 36]  + sG[i1 + (16 + 8 + jj) * 36]  + bias1[2];
                const float go_ = sG[i0 + (16 + 12 + jj) * 36] + sG[i1 + (16 + 12 + jj) * 36] + bias1[3];
                const float iG = 1.f / (1.f + expf(-gi_));
                const float fG = 1.f / (1.f + expf(-gf_));
                const float gT = tanhf(gg_);
                const float oG = 1.f / (1.f + expf(-go_));
                c1 = fmaf(fG, c1, iG * gT);
                const float h = oG * tanhf(c1);
                store_h_pair(h1n, hoff1, f2bf(h), l);
            }
        }
        // ---- layer1-done signal + windowed fence (1/NSLOT iters, non-polling wave)
        asm volatile("s_waitcnt vmcnt(0)" ::: "memory");
        __syncthreads();
        if (tid == 0) st_u32_llc(f1g + jb, (unsigned)(it + 1));
        if ((it & 7) == 7 && tid >= 448)
            __builtin_amdgcn_fence(__ATOMIC_ACQUIRE, "agent");
    }

    // ---- head: out[b] = h1[TT-1] . w + b (slot 7; all layer1 done first)
    if (jb == 0) {
        if (tid < 128) {
            unsigned* p = f1g + tid;
            while ((int)ld_u32_llc(p) < TT + 1) __builtin_amdgcn_s_sleep(2);
        }
        __syncthreads();
        const unsigned short* h1h = h1base + (size_t)((TT + 7) & 7) * SLOT_SH;
        const int bl_ = tid >> 2;
        const int qd  = tid & 3;
        const int b   = g * 128 + bl_;
        const int btw = b >> 4;
        float s = 0.f;
        #pragma unroll
        for (int jt = qd * 4; jt < qd * 4 + 4; ++jt) {
            #pragma unroll
            for (int q2 = 0; q2 < 4; ++q2) {
                const size_t off = (((size_t)btw * 16 + jt) * 64 + ((b & 15) | (q2 << 4))) * 8;
                short8 vh = *(const short8*)&h1h[off];
                const int j0 = jt * 32 + q2 * 8;
                #pragma unroll
                for (int e = 0; e < 8; ++e)
                    s += bf2f((unsigned short)vh[e]) * headw[j0 + e];
            }
        }
        s += __shfl_down(s, 2, 4);
        s += __shfl_down(s, 1, 4);
        if (qd == 0) out[b] = s + headb[0];
    }
}

extern "C" void kernel_launch(void* const* d_in, const int* in_sizes, int n_in,
                              void* d_out, int out_size, void* d_ws, size_t ws_size,
                              hipStream_t stream) {
    const float* x      = (const float*)d_in[0];
    const float* W_ih0  = (const float*)d_in[1];
    const float* W_hh0  = (const float*)d_in[2];
    const float* b_ih0  = (const float*)d_in[3];
    const float* b_hh0  = (const float*)d_in[4];
    const float* W_ih1  = (const float*)d_in[5];
    const float* W_hh1  = (const float*)d_in[6];
    const float* b_ih1  = (const float*)d_in[7];
    const float* b_hh1  = (const float*)d_in[8];
    const float* head_w = (const float*)d_in[9];
    const float* head_b = (const float*)d_in[10];
    float* out = (float*)d_out;

    // ws layout: [flags 4KB (f0 g0,g1 | f1 g0,g1)][pad to 1MB][h0: 8x256KB][h1: 8x256KB]
    const size_t SLOT_BYTES = (size_t)SLOT_SH * 2;          // 256 KB
    unsigned* gf = (unsigned*)d_ws;
    unsigned short* h0base = (unsigned short*)((char*)d_ws + (1 << 20));
    unsigned short* h1base = (unsigned short*)((char*)d_ws + (1 << 20) + NSLOT * SLOT_BYTES);

    // zero: flags + the t=-1 slots (slot 7 of each chain)
    hipMemsetAsync(d_ws, 0, 4096, stream);
    hipMemsetAsync((char*)h0base + 7 * SLOT_BYTES, 0, SLOT_BYTES, stream);
    hipMemsetAsync((char*)h1base + 7 * SLOT_BYTES, 0, SLOT_BYTES, stream);

    hipFuncSetAttribute((const void*)lstm_persistent,
                        hipFuncAttributeMaxDynamicSharedMemorySize, LDS_BYTES);
    lstm_persistent<<<dim3(256), dim3(512), LDS_BYTES, stream>>>(
        x, W_ih0, W_hh0, b_ih0, b_hh0, W_ih1, W_hh1, b_ih1, b_hh1,
        head_w, head_b, h0base, h1base, gf, out);
}

// Round 14
// 1886.153 us; speedup vs baseline: 1.4379x; 1.4379x over previous
//
#include <hip/hip_runtime.h>

#define HID 512
#define NB  256
#define TT  256
#define DIN 64
#define HBUF 131072                  // shorts per h panel (bf16 hi only)
#define SLOT_SH HBUF                 // slot = one panel (256 KB)
#define NSLOT 8                      // rotation depth; fence every NSLOT iters

typedef __attribute__((ext_vector_type(8))) short short8;
typedef __attribute__((ext_vector_type(4))) float f32x4;

__device__ __forceinline__ unsigned short f2bf(float f) {
    unsigned int u = __float_as_uint(f);
    u += 0x7FFF + ((u >> 16) & 1);
    return (unsigned short)(u >> 16);
}
__device__ __forceinline__ float bf2f(unsigned short h) {
    return __uint_as_float(((unsigned int)h) << 16);
}

// fast activations: v_exp_f32 + v_rcp_f32 (error ~1e-6, budget 7.2e-4)
__device__ __forceinline__ float fsig(float x) {
    return __builtin_amdgcn_rcpf(1.f + __expf(-x));
}
__device__ __forceinline__ float ftanh(float x) {
    return 1.f - 2.f * __builtin_amdgcn_rcpf(1.f + __expf(2.f * x));
}

// ---- LLC-coherent (cross-XCD) 4B access, explicit sc0/sc1 cache bits ----
__device__ __forceinline__ void st_u32_llc(unsigned* p, unsigned v) {
    asm volatile("global_store_dword %0, %1, off sc0 sc1" :: "v"(p), "v"(v) : "memory");
}
__device__ __forceinline__ unsigned ld_u32_llc(const unsigned* p) {
    unsigned v;
    asm volatile("global_load_dword %0, %1, off sc0 sc1\n\ts_waitcnt vmcnt(0)"
                 : "=v"(v) : "v"(p) : "memory");
    return v;
}

// h-A operand is single bf16: 2-term split (A.Bh + A.Bl)
#define MFMA2(acc, a, bh, bl)                                               \
    acc = __builtin_amdgcn_mfma_f32_16x16x32_bf16(a, bh, acc, 0, 0, 0);     \
    acc = __builtin_amdgcn_mfma_f32_16x16x32_bf16(a, bl, acc, 0, 0, 0);
// x-A operand keeps hi/lo: 3-term split
#define MFMA3(acc, ah, al, bh, bl)                                          \
    acc = __builtin_amdgcn_mfma_f32_16x16x32_bf16(ah, bh, acc, 0, 0, 0);    \
    acc = __builtin_amdgcn_mfma_f32_16x16x32_bf16(ah, bl, acc, 0, 0, 0);    \
    acc = __builtin_amdgcn_mfma_f32_16x16x32_bf16(al, bh, acc, 0, 0, 0);

// LDS layout (shorts): sW0 h/l: 18*512 each; sW1 h/l: 32*512 each; then sG floats
#define SW0_N 9216
#define SW1_N 16384
#define LDS_BYTES ((SW0_N * 2 + SW1_N * 2) * 2 + 128 * 17 * 4)

// packed 2-lane h store: lanes (l, l+1) hold adjacent j; even lane stores u32
__device__ __forceinline__ void store_h_pair(unsigned short* buf, size_t hoff,
                                             unsigned short v, int l) {
    unsigned int hv = (unsigned int)v;
    unsigned int up = __shfl_down(hv, 1);
    if ((l & 1) == 0)
        st_u32_llc((unsigned*)(buf + hoff), hv | (up << 16));
}

// wait: 128 lanes poll one flag each (LLC loads, no cache pollution), then barrier
__device__ __forceinline__ void flag_wait(unsigned* fset, int target) {
    if (threadIdx.x < 128) {
        unsigned* p = fset + threadIdx.x;
        while ((int)ld_u32_llc(p) < target) __builtin_amdgcn_s_sleep(2);
    }
    __syncthreads();
}

__global__ __launch_bounds__(512, 2) void lstm_persistent(
    const float* __restrict__ x,
    const float* __restrict__ Wih0, const float* __restrict__ Whh0,
    const float* __restrict__ bih0, const float* __restrict__ bhh0,
    const float* __restrict__ Wih1, const float* __restrict__ Whh1,
    const float* __restrict__ bih1, const float* __restrict__ bhh1,
    const float* __restrict__ headw, const float* __restrict__ headb,
    unsigned short* h0base, unsigned short* h1base,
    unsigned* gf, float* __restrict__ out)
{
    extern __shared__ unsigned short lds[];
    unsigned short* sW0h = lds;
    unsigned short* sW0l = sW0h + SW0_N;
    unsigned short* sW1h = sW0l + SW0_N;
    unsigned short* sW1l = sW1h + SW1_N;
    float* sG = (float*)(sW1l + SW1_N);          // [128][17]

    const int tid = threadIdx.x;
    const int l   = tid & 63;
    const int w   = tid >> 6;         // wave 0..7
    const int bid = blockIdx.x;
    const int g   = bid & 1;          // batch group
    const int jb  = bid >> 1;         // j-block 0..127 (hidden units jb*4..jb*4+3)

    unsigned* f0g = gf + g * 128;            // layer0-done flags (this group)
    unsigned* f1g = gf + 256 + g * 128;      // layer1-done flags (this group)

    // ---- weight preload: fp32 -> hi/lo bf16 fragments in LDS ----
    const int r  = l & 15;
    const int ks = (l >> 4) * 8;
    const int n  = (r >> 2) * HID + jb * 4 + (r & 3);
    {
        for (int kt = w; kt < 18; kt += 8) {
            const float* src = (kt < 2) ? (Wih0 + (size_t)n * DIN + kt * 32 + ks)
                                        : (Whh0 + (size_t)n * HID + (kt - 2) * 32 + ks);
            float v[8];
            *(float4*)&v[0] = *(const float4*)src;
            *(float4*)&v[4] = *(const float4*)(src + 4);
            union { unsigned short u[8]; uint4 q; } ph, pl;
            #pragma unroll
            for (int e = 0; e < 8; ++e) {
                unsigned short h = f2bf(v[e]);
                ph.u[e] = h; pl.u[e] = f2bf(v[e] - bf2f(h));
            }
            *(uint4*)&sW0h[(kt * 64 + l) * 8] = ph.q;
            *(uint4*)&sW0l[(kt * 64 + l) * 8] = pl.q;
        }
        for (int kt = w; kt < 32; kt += 8) {
            const float* src = (kt < 16) ? (Wih1 + (size_t)n * HID + kt * 32 + ks)
                                         : (Whh1 + (size_t)n * HID + (kt - 16) * 32 + ks);
            float v[8];
            *(float4*)&v[0] = *(const float4*)src;
            *(float4*)&v[4] = *(const float4*)(src + 4);
            union { unsigned short u[8]; uint4 q; } ph, pl;
            #pragma unroll
            for (int e = 0; e < 8; ++e) {
                unsigned short h = f2bf(v[e]);
                ph.u[e] = h; pl.u[e] = f2bf(v[e] - bf2f(h));
            }
            *(uint4*)&sW1h[(kt * 64 + l) * 8] = ph.q;
            *(uint4*)&sW1l[(kt * 64 + l) * 8] = pl.q;
        }
    }

    float bias0[4], bias1[4];
    #pragma unroll
    for (int gi = 0; gi < 4; ++gi) {
        const int nn = gi * HID + jb * 4 + (l & 3);
        bias0[gi] = bih0[nn] + bhh0[nn];
        bias1[gi] = bih1[nn] + bhh1[nn];
    }
    float c0 = 0.f, c1 = 0.f;

    const int jj      = l & 3;
    const int b_local = 16 * w + (l >> 2);
    const int b_glob  = g * 128 + b_local;
    const int j_glob  = jb * 4 + jj;
    const size_t hoff = ((((size_t)(b_glob >> 4)) * 16 + (j_glob >> 5)) * 64
                         + ((b_glob & 15) | (((j_glob >> 3) & 3) << 4))) * 8 + (j_glob & 7);
    const int bt = g * 8 + w;        // this wave's global batch tile

    // x prefetch registers
    const int xrow = g * 128 + w * 16 + (l & 15);
    float xv0[8], xv1[8];
    {
        const float* s0 = x + ((size_t)xrow * TT + 0) * DIN + ks;
        *(float4*)&xv0[0] = *(const float4*)s0;
        *(float4*)&xv0[4] = *(const float4*)(s0 + 4);
        *(float4*)&xv1[0] = *(const float4*)(s0 + 32);
        *(float4*)&xv1[4] = *(const float4*)(s0 + 36);
    }

    __syncthreads();                 // weights ready

    // x-part B fragments pinned in VGPRs (static all iterations)
    const short8 bx0h = *(const short8*)&sW0h[(0 * 64 + l) * 8];
    const short8 bx0l = *(const short8*)&sW0l[(0 * 64 + l) * 8];
    const short8 bx1h = *(const short8*)&sW0h[(1 * 64 + l) * 8];
    const short8 bx1l = *(const short8*)&sW0l[(1 * 64 + l) * 8];

    for (int it = 0; it <= TT; ++it) {
        // ---- wait 1: layer0 of it-1 done everywhere (signaled MID-iteration -> fast)
        flag_wait(f0g, it);

        // slot map: h0[t] -> slot t&7 ; h1[t] -> slot t&7
        const unsigned short* h0c = h0base + (size_t)((it + 7) & 7) * SLOT_SH;  // h0[it-1]
        unsigned short* h0n       = h0base + (size_t)(it & 7) * SLOT_SH;        // h0[it]
        const unsigned short* h1c = h1base + (size_t)((it + 6) & 7) * SLOT_SH;  // h1[it-2]
        unsigned short* h1n       = h1base + (size_t)((it + 7) & 7) * SLOT_SH;  // h1[it-1]

        f32x4 acc0[2] = {{0.f,0.f,0.f,0.f},{0.f,0.f,0.f,0.f}};
        f32x4 acc1[2] = {{0.f,0.f,0.f,0.f},{0.f,0.f,0.f,0.f}};

        // ---- hoisted h0[it-1] A-fragments (bf16): 16 b128 loads batched (MLP),
        // ---- used by layer0 (W0hh) AND layer1 ys0-part (W1ih)
        short8 fAh[16];
        #pragma unroll
        for (int kt = 0; kt < 16; ++kt) {
            const size_t o = (((size_t)bt * 16 + kt) * 64 + l) * 8;
            fAh[kt] = *(const short8*)&h0c[o];
        }

        // ================= layer 0, t = it =================
        if (it < TT) {
            // x part: register B fragments (no LDS)
            {
                union { unsigned short u[8]; short8 s; } ah, al;
                #pragma unroll
                for (int e = 0; e < 8; ++e) {
                    unsigned short h = f2bf(xv0[e]);
                    ah.u[e] = h; al.u[e] = f2bf(xv0[e] - bf2f(h));
                }
                MFMA3(acc0[0], ah.s, al.s, bx0h, bx0l);
                #pragma unroll
                for (int e = 0; e < 8; ++e) {
                    unsigned short h = f2bf(xv1[e]);
                    ah.u[e] = h; al.u[e] = f2bf(xv1[e] - bf2f(h));
                }
                MFMA3(acc0[1], ah.s, al.s, bx1h, bx1l);
            }
            #pragma unroll
            for (int kt = 0; kt < 16; ++kt) {
                short8 bh = *(const short8*)&sW0h[((kt + 2) * 64 + l) * 8];
                short8 bl = *(const short8*)&sW0l[((kt + 2) * 64 + l) * 8];
                MFMA2(acc0[kt & 1], fAh[kt], bh, bl);
            }
            #pragma unroll
            for (int q = 0; q < 4; ++q)
                sG[(16 * w + (l >> 4) * 4 + q) * 17 + (l & 15)] = acc0[0][q] + acc0[1][q];
            __syncthreads();
            {
                const float gi_ = sG[b_local * 17 + jj]      + bias0[0];
                const float gf_ = sG[b_local * 17 + 4 + jj]  + bias0[1];
                const float gg_ = sG[b_local * 17 + 8 + jj]  + bias0[2];
                const float go_ = sG[b_local * 17 + 12 + jj] + bias0[3];
                const float iG = fsig(gi_);
                const float fG = fsig(gf_);
                const float gT = ftanh(gg_);
                const float oG = fsig(go_);
                c0 = fmaf(fG, c0, iG * gT);
                const float h = oG * ftanh(c0);
                store_h_pair(h0n, hoff, f2bf(h), l);
            }
            // ---- EARLY layer0-done signal: unblocks next iteration's wait-1
            asm volatile("s_waitcnt vmcnt(0)" ::: "memory");
            __syncthreads();
            if (tid == 0) st_u32_llc(f0g + jb, (unsigned)(it + 1));
        }

        // prefetch x[it+1]
        if (it + 1 < TT) {
            const float* s0 = x + ((size_t)xrow * TT + (it + 1)) * DIN + ks;
            *(float4*)&xv0[0] = *(const float4*)s0;
            *(float4*)&xv0[4] = *(const float4*)(s0 + 4);
            *(float4*)&xv1[0] = *(const float4*)(s0 + 32);
            *(float4*)&xv1[4] = *(const float4*)(s0 + 36);
        }

        // ---- ys0-part of layer1: needs only fAh (guarded by wait-1) + static sW1.
        // ---- Runs BEFORE wait-2 so only the h1-half remains on the post-wait path.
        if (it > 0) {
            #pragma unroll
            for (int kt = 0; kt < 16; ++kt) {
                short8 bh = *(const short8*)&sW1h[(kt * 64 + l) * 8];
                short8 bl = *(const short8*)&sW1l[(kt * 64 + l) * 8];
                MFMA2(acc1[kt & 1], fAh[kt], bh, bl);
            }
        }

        // ---- wait 2: layer1 of it-1 done everywhere (covers h1[it-2] writes)
        flag_wait(f1g, it);

        // ================= layer 1 (h1 half), t = it-1 =================
        if (it > 0) {
            // h1[it-2] part: batched fragment loads (MLP), then MFMAs
            short8 fCh[16];
            #pragma unroll
            for (int kt = 0; kt < 16; ++kt) {
                const size_t o = (((size_t)bt * 16 + kt) * 64 + l) * 8;
                fCh[kt] = *(const short8*)&h1c[o];
            }
            #pragma unroll
            for (int kt = 0; kt < 16; ++kt) {
                short8 bh = *(const short8*)&sW1h[((kt + 16) * 64 + l) * 8];
                short8 bl = *(const short8*)&sW1l[((kt + 16) * 64 + l) * 8];
                MFMA2(acc1[kt & 1], fCh[kt], bh, bl);
            }
            #pragma unroll
            for (int q = 0; q < 4; ++q)
                sG[(16 * w + (l >> 4) * 4 + q) * 17 + (l & 15)] = acc1[0][q] + acc1[1][q];
            __syncthreads();
            {
                const float gi_ = sG[b_local * 17 + jj]      + bias1[0];
                const float gf_ = sG[b_local * 17 + 4 + jj]  + bias1[1];
                const float gg_ = sG[b_local * 17 + 8 + jj]  + bias1[2];
                const float go_ = sG[b_local * 17 + 12 + jj] + bias1[3];
                const float iG = fsig(gi_);
                const float fG = fsig(gf_);
                const float gT = ftanh(gg_);
                const float oG = fsig(go_);
                c1 = fmaf(fG, c1, iG * gT);
                const float h = oG * ftanh(c1);
                store_h_pair(h1n, hoff, f2bf(h), l);
            }
        }
        // ---- layer1-done signal + windowed fence (1/NSLOT iters, non-polling wave)
        asm volatile("s_waitcnt vmcnt(0)" ::: "memory");
        __syncthreads();
        if (tid == 0) st_u32_llc(f1g + jb, (unsigned)(it + 1));
        if ((it & 7) == 7 && tid >= 448)
            __builtin_amdgcn_fence(__ATOMIC_ACQUIRE, "agent");
    }

    // ---- head: out[b] = h1[TT-1] . w + b (slot 7; all layer1 done first)
    if (jb == 0) {
        if (tid < 128) {
            unsigned* p = f1g + tid;
            while ((int)ld_u32_llc(p) < TT + 1) __builtin_amdgcn_s_sleep(2);
        }
        __syncthreads();
        const unsigned short* h1h = h1base + (size_t)((TT + 7) & 7) * SLOT_SH;
        const int bl_ = tid >> 2;
        const int qd  = tid & 3;
        const int b   = g * 128 + bl_;
        const int btw = b >> 4;
        float s = 0.f;
        #pragma unroll
        for (int jt = qd * 4; jt < qd * 4 + 4; ++jt) {
            #pragma unroll
            for (int q2 = 0; q2 < 4; ++q2) {
                const size_t off = (((size_t)btw * 16 + jt) * 64 + ((b & 15) | (q2 << 4))) * 8;
                short8 vh = *(const short8*)&h1h[off];
                const int j0 = jt * 32 + q2 * 8;
                #pragma unroll
                for (int e = 0; e < 8; ++e)
                    s += bf2f((unsigned short)vh[e]) * headw[j0 + e];
            }
        }
        s += __shfl_down(s, 2, 4);
        s += __shfl_down(s, 1, 4);
        if (qd == 0) out[b] = s + headb[0];
    }
}

extern "C" void kernel_launch(void* const* d_in, const int* in_sizes, int n_in,
                              void* d_out, int out_size, void* d_ws, size_t ws_size,
                              hipStream_t stream) {
    const float* x      = (const float*)d_in[0];
    const float* W_ih0  = (const float*)d_in[1];
    const float* W_hh0  = (const float*)d_in[2];
    const float* b_ih0  = (const float*)d_in[3];
    const float* b_hh0  = (const float*)d_in[4];
    const float* W_ih1  = (const float*)d_in[5];
    const float* W_hh1  = (const float*)d_in[6];
    const float* b_ih1  = (const float*)d_in[7];
    const float* b_hh1  = (const float*)d_in[8];
    const float* head_w = (const float*)d_in[9];
    const float* head_b = (const float*)d_in[10];
    float* out = (float*)d_out;

    // ws layout: [flags 4KB (f0 g0,g1 | f1 g0,g1)][pad to 1MB][h0: 8x256KB][h1: 8x256KB]
    const size_t SLOT_BYTES = (size_t)SLOT_SH * 2;          // 256 KB
    unsigned* gf = (unsigned*)d_ws;
    unsigned short* h0base = (unsigned short*)((char*)d_ws + (1 << 20));
    unsigned short* h1base = (unsigned short*)((char*)d_ws + (1 << 20) + NSLOT * SLOT_BYTES);

    // zero: flags + the t=-1 slots (slot 7 of each chain)
    hipMemsetAsync(d_ws, 0, 4096, stream);
    hipMemsetAsync((char*)h0base + 7 * SLOT_BYTES, 0, SLOT_BYTES, stream);
    hipMemsetAsync((char*)h1base + 7 * SLOT_BYTES, 0, SLOT_BYTES, stream);

    hipFuncSetAttribute((const void*)lstm_persistent,
                        hipFuncAttributeMaxDynamicSharedMemorySize, LDS_BYTES);
    lstm_persistent<<<dim3(256), dim3(512), LDS_BYTES, stream>>>(
        x, W_ih0, W_hh0, b_ih0, b_hh0, W_ih1, W_hh1, b_ih1, b_hh1,
        head_w, head_b, h0base, h1base, gf, out);
}